// Round 6
// baseline (386.692 us; speedup 1.0000x reference)
//
#include <hip/hip_runtime.h>
#include <hip/hip_fp16.h>
#include <math.h>

// ---------------------------------------------------------------------------
// GAT encoder, 2 layers.
//   GEMMs: single-term fp16 MFMA (mfma_f32_16x16x32_f16, fp32 accum),
//          2-phase LDS double-buffer: one barrier per K-step; store of the
//          prefetched tile and issue of the tile-after-next's global loads
//          overlap the current step's MFMA. LDS padded 32->34 shorts
//          (stride 68B -> bank start 17*r mod 32: conflict-free reads).
//   Padded CSR: per-node degree rounded up to even; holes carry sentinel
//          records (src=0, w=0) so the aggregate inner loop has NO clamps
//          and NO tail checks.
//   fill_rec (2 edges/thread) computes w = exp(leaky(a_s[src]+a_d[dst]))
//          per edge per head; rec[i] = {src, w0|w1, w2|w3, 0} (fp16).
//   Aggregation: 1 node/wave, 2 edges/iteration (lanes 0-31 edge p, lanes
//          32-63 edge p+1; 16B/lane -> one 1KB gather per pair), depth-4
//          rotation-free software pipeline, prefetch distance 8 edges.
//          At the random-access L2-miss/L3-service floor (~3.8 TB/s eff).
// ---------------------------------------------------------------------------

#define LEAKY_SLOPE 0.2f

typedef __attribute__((ext_vector_type(8))) short short8v;      // 16B
typedef __attribute__((ext_vector_type(8))) _Float16 half8v;    // 8 fp16
typedef __attribute__((ext_vector_type(4))) float float4v;

// ---------------- fused prep: W->fp16 transposed + x->fp16 + histogram -----

__global__ void prep_kernel(const float* __restrict__ W1, __half* __restrict__ Bt1,
                            const float* __restrict__ W2, __half* __restrict__ Bt2,
                            const float* __restrict__ x, __half* __restrict__ x_h,
                            const int* __restrict__ ei, int* __restrict__ cnt,
                            int E, int N, int xblocks) {
    int b = blockIdx.x;
    if (b < 128) {                       // W1: [128][256] -> Bt1[c*128+k]
        int idx = b * 256 + threadIdx.x;
        int k = idx >> 8, c = idx & 255;
        Bt1[c * 128 + k] = __float2half(W1[idx]);
    } else if (b < 384) {                // W2: [256][256] -> Bt2[c*256+k]
        int idx = (b - 128) * 256 + threadIdx.x;
        int k = idx >> 8, c = idx & 255;
        Bt2[c * 256 + k] = __float2half(W2[idx]);
    } else if (b < 384 + xblocks) {      // x -> fp16, 4 elems/thread
        int t = (b - 384) * 256 + threadIdx.x;
        if (t < N * 32) {
            float4 v = *(const float4*)&x[(size_t)t * 4];
            __half2 h01 = __floats2half2_rn(v.x, v.y);
            __half2 h23 = __floats2half2_rn(v.z, v.w);
            uint2 pk = {*(unsigned*)&h01, *(unsigned*)&h23};
            *(uint2*)&x_h[(size_t)t * 4] = pk;
        }
    } else {                             // degree histogram (incl. self-loops)
        int e = (b - 384 - xblocks) * 256 + threadIdx.x;
        if (e < E + N) {
            int dst = (e < E) ? ei[E + e] : (e - E);
            atomicAdd(&cnt[dst], 1);
        }
    }
}

// ---------------- CSR build (padded to even degree) ----------------

__global__ __launch_bounds__(1024) void scan_block(const int* __restrict__ cnt,
                                                   int* __restrict__ row_start,
                                                   int* __restrict__ partials,
                                                   int n) {
    __shared__ int wsum[16];
    int tid = threadIdx.x, lane = tid & 63, wid = tid >> 6;
    int gi = blockIdx.x * 1024 + tid;
    int v = (gi < n) ? ((cnt[gi] + 1) & ~1) : 0;   // pad degree to even
    int x = v;
#pragma unroll
    for (int off = 1; off < 64; off <<= 1) {
        int y = __shfl_up(x, off, 64);
        if (lane >= off) x += y;
    }
    if (lane == 63) wsum[wid] = x;
    __syncthreads();
    if (wid == 0 && lane < 16) {
        int w = wsum[lane];
#pragma unroll
        for (int off = 1; off < 16; off <<= 1) {
            int y = __shfl_up(w, off, 16);
            if (lane >= off) w += y;
        }
        wsum[lane] = w;
    }
    __syncthreads();
    int excl = x - v + ((wid > 0) ? wsum[wid - 1] : 0);
    if (gi < n) row_start[gi] = excl;
    if (tid == 1023) partials[blockIdx.x] = wsum[15];
}

// scan_add with the partials-scan folded in (wave 0 redundantly scans <=64
// partials; saves the scan_partials launch).
__global__ __launch_bounds__(1024) void scan_add(int* __restrict__ row_start,
                                                 const int* __restrict__ partials,
                                                 int n, int nb) {
    __shared__ int spart[2];             // [excl prefix for this block, total]
    if (threadIdx.x < 64) {
        int lane = threadIdx.x;
        int v = (lane < nb) ? partials[lane] : 0;
        int x = v;
#pragma unroll
        for (int off = 1; off < 64; off <<= 1) {
            int y = __shfl_up(x, off, 64);
            if (lane >= off) x += y;
        }
        if (lane == (int)blockIdx.x) spart[0] = x - v;   // exclusive prefix
        if (lane == nb - 1) spart[1] = x;                // grand total
    }
    __syncthreads();
    int gi = blockIdx.x * 1024 + threadIdx.x;
    if (gi < n) row_start[gi] += spart[0];
    if (gi == 0) row_start[n] = spart[1];
}

__global__ void scatter_kernel(const int* __restrict__ ei,
                               const int* __restrict__ row_start,
                               int* __restrict__ fill,
                               int2* __restrict__ edge_sd, int E, int Etot) {
    int e = blockIdx.x * blockDim.x + threadIdx.x;
    if (e >= Etot) return;
    int src, dst;
    if (e < E) { src = ei[e]; dst = ei[E + e]; }
    else       { src = e - E; dst = e - E; }
    int pos = row_start[dst] + atomicAdd(&fill[dst], 1);
    edge_sd[pos] = make_int2(src, dst);
}

// rec[i] = {src, w0|w1, w2|w3, pad}, w = exp(leaky(a_s+a_d)) fp16.
// Sentinel slots (edge_sd memset 0xFF) -> zero record. 2 edges per thread.
__device__ __forceinline__ uint4 make_rec(int src, int dst,
                                          const __half* __restrict__ a_s_h,
                                          const float* __restrict__ a_d) {
    if (src < 0) {
        uint4 z = {0u, 0u, 0u, 0u};
        return z;
    }
    uint2 as2 = *(const uint2*)&a_s_h[(size_t)src * 4];
    float4 ad4 = *(const float4*)&a_d[(size_t)dst * 4];
    float2 f01 = __half22float2(*(const __half2*)&as2.x);
    float2 f23 = __half22float2(*(const __half2*)&as2.y);
    float e0 = f01.x + ad4.x, e1 = f01.y + ad4.y;
    float e2 = f23.x + ad4.z, e3 = f23.y + ad4.w;
    e0 = (e0 > 0.f) ? e0 : LEAKY_SLOPE * e0;
    e1 = (e1 > 0.f) ? e1 : LEAKY_SLOPE * e1;
    e2 = (e2 > 0.f) ? e2 : LEAKY_SLOPE * e2;
    e3 = (e3 > 0.f) ? e3 : LEAKY_SLOPE * e3;
    __half2 w01 = __floats2half2_rn(__expf(e0), __expf(e1));
    __half2 w23 = __floats2half2_rn(__expf(e2), __expf(e3));
    uint4 r = {(unsigned)src, *(unsigned*)&w01, *(unsigned*)&w23, 0u};
    return r;
}

__global__ void fill_rec(const int4* __restrict__ edge_sd2,
                         const __half* __restrict__ a_s_h,
                         const float* __restrict__ a_d,
                         uint4* __restrict__ rec, int npairs) {
    int i = blockIdx.x * blockDim.x + threadIdx.x;
    if (i >= npairs) return;
    int4 sd = edge_sd2[i];               // {src0,dst0,src1,dst1}
    uint4 r0 = make_rec(sd.x, sd.y, a_s_h, a_d);
    uint4 r1 = make_rec(sd.z, sd.w, a_s_h, a_d);
    rec[2 * i] = r0;
    rec[2 * i + 1] = r1;
}

// ---------------- fp16 MFMA GEMM + fused attention dots ---------------
// C[M,256] = A[M,K] @ B[K,256], C stored fp16. A fp16, B fp16 transposed.
// 128x128 tile, BK=32, 2x2 waves, 16 mfma per K-step.
// 2-phase LDS double-buffer: one barrier per K-step.

template <int K>
__global__ __launch_bounds__(256) void gemm_mfma(
    const __half* __restrict__ Ah, const __half* __restrict__ Bt,
    __half* __restrict__ Ch,
    const float* __restrict__ att_src, const float* __restrict__ att_dst,
    __half* __restrict__ a_s_out, float* __restrict__ a_d_out, int M) {
    constexpr int NS = K / 32;          // K-steps
    __shared__ short As[2][128][34];    // pad 32->34: stride 68B, bank start
    __shared__ short Bs[2][128][34];    //   17*r mod 32 -> conflict-free

    const int col0 = (blockIdx.x & 1) * 128;
    const int row0 = (blockIdx.x >> 1) * 128;
    const int tid = threadIdx.x;
    const int lane = tid & 63;
    const int wave = tid >> 6;
    const int wr = wave >> 1, wc = wave & 1;
    const int quad = lane >> 4, lc = lane & 15;

    float4v acc[4][4] = {};

    const short* Abits = (const short*)Ah;
    const short* Bbits = (const short*)Bt;

    // staging geometry: thread covers rows (tid>>2) and (tid>>2)+64,
    // k-chunk (tid&3)*8, for both A and B.
    const int sr = tid >> 2;
    const int ko = (tid & 3) * 8;
    const int ga0 = row0 + sr, ga1 = ga0 + 64;
    const size_t gb0 = (size_t)(col0 + sr) * K + ko;
    const size_t gb1 = (size_t)(col0 + sr + 64) * K + ko;

    short8v pa0, pa1, pb0, pb1;

#define LOADT(k0)                                                          \
    {                                                                      \
        pa0 = {}; pa1 = {};                                                \
        if (ga0 < M) pa0 = *(const short8v*)&Abits[(size_t)ga0 * K + (k0) + ko]; \
        if (ga1 < M) pa1 = *(const short8v*)&Abits[(size_t)ga1 * K + (k0) + ko]; \
        pb0 = *(const short8v*)&Bbits[gb0 + (k0)];                         \
        pb1 = *(const short8v*)&Bbits[gb1 + (k0)];                         \
    }
#define STORET(buf)                                                        \
    {                                                                      \
        *(short8v*)&As[buf][sr][ko] = pa0;                                 \
        *(short8v*)&As[buf][sr + 64][ko] = pa1;                            \
        *(short8v*)&Bs[buf][sr][ko] = pb0;                                 \
        *(short8v*)&Bs[buf][sr + 64][ko] = pb1;                            \
    }

    LOADT(0);
    STORET(0);
    if (NS > 1) LOADT(32);
    __syncthreads();

#pragma unroll
    for (int s = 0; s < NS; s++) {
        const int cur = s & 1;
        // regs hold tile s+1: store into the other buffer, then issue
        // tile s+2's global loads; both overlap this step's ds_read+MFMA.
        if (s + 1 < NS) {
            STORET(cur ^ 1);
            if (s + 2 < NS) LOADT((s + 2) * 32);
        }
        half8v a[4], bv[4];
#pragma unroll
        for (int mt = 0; mt < 4; mt++) {
            int r = wr * 64 + mt * 16 + lc;
            a[mt] = *(const half8v*)&As[cur][r][quad * 8];
        }
#pragma unroll
        for (int nt = 0; nt < 4; nt++) {
            int n = wc * 64 + nt * 16 + lc;
            bv[nt] = *(const half8v*)&Bs[cur][n][quad * 8];
        }
#pragma unroll
        for (int mt = 0; mt < 4; mt++)
#pragma unroll
            for (int nt = 0; nt < 4; nt++)
                acc[mt][nt] = __builtin_amdgcn_mfma_f32_16x16x32_f16(
                    a[mt], bv[nt], acc[mt][nt], 0, 0, 0);
        __syncthreads();   // reads of buf[cur] done; stores to buf[cur^1] visible
    }
#undef LOADT
#undef STORET

    // ---- epilogue: wave's 64 cols = head; C/D: col=lc(+nt*16), row=quad*4+r
    const int head = (col0 >> 6) + wc;
    float as_c[4], ad_c[4];
#pragma unroll
    for (int nt = 0; nt < 4; nt++) {
        as_c[nt] = att_src[head * 64 + nt * 16 + lc];
        ad_c[nt] = att_dst[head * 64 + nt * 16 + lc];
    }

#pragma unroll
    for (int mt = 0; mt < 4; mt++) {
#pragma unroll
        for (int r = 0; r < 4; r++) {
            int gr = row0 + wr * 64 + mt * 16 + quad * 4 + r;
            float ps = 0.f, pd = 0.f;
#pragma unroll
            for (int nt = 0; nt < 4; nt++) {
                float c = acc[mt][nt][r];
                ps = fmaf(c, as_c[nt], ps);
                pd = fmaf(c, ad_c[nt], pd);
                if (gr < M)
                    Ch[(size_t)gr * 256 + col0 + wc * 64 + nt * 16 + lc] =
                        __float2half(c);
            }
#pragma unroll
            for (int off = 1; off < 16; off <<= 1) {
                ps += __shfl_xor(ps, off, 64);
                pd += __shfl_xor(pd, off, 64);
            }
            if (lc == 0 && gr < M) {
                a_s_out[gr * 4 + head] = __float2half(ps);
                a_d_out[gr * 4 + head] = pd;
            }
        }
    }
}

// ---------------- fused aggregate + bias + elu ----------------
// 1 node/wave, 2 edges/iteration, padded-even rows: no clamps, no tail
// checks. Depth-4 rotation-free pipeline, prefetch distance 8 edges.
// At the random-access L2-miss/L3-service floor (~3.8 TB/s effective).

template <bool OUT_HALF>
__global__ __launch_bounds__(256) void gat_aggregate(
    const __half* __restrict__ hh, const uint4* __restrict__ rec,
    const int* __restrict__ row_start, const float* __restrict__ bias,
    void* __restrict__ outp, int n) {
    int node = (blockIdx.x * blockDim.x + threadIdx.x) >> 6;
    if (node >= n) return;                 // wave-uniform
    int lane = threadIdx.x & 63;
    int half = lane >> 5, l32 = lane & 31;
    int head = l32 >> 3;
    unsigned wsh = (head & 1) << 4;        // 16-bit select shift, hoisted

    int beg = row_start[node];
    int end = row_start[node + 1];         // end-beg even, >= 2

    float l = 0.f;
    float acc[8] = {};

    uint4 r0 = rec[beg + half];
    uint4 r1 = rec[beg + 2 + half];
    uint4 r2 = rec[beg + 4 + half];
    uint4 r3 = rec[beg + 6 + half];

#define GATH(rr) (*(const uint4*)&hh[(size_t)(rr).x * 256 + l32 * 8])
#define PROC(rr, vv)                                                      \
    {                                                                     \
        unsigned u = (head & 2) ? (rr).z : (rr).y;                        \
        unsigned short us = (unsigned short)(u >> wsh);                   \
        float w = __half2float(*(const __half*)&us);                      \
        l += w;                                                           \
        const __half2* hp = (const __half2*)&(vv);                        \
        float2 f0 = __half22float2(hp[0]);                                \
        float2 f1 = __half22float2(hp[1]);                                \
        float2 f2 = __half22float2(hp[2]);                                \
        float2 f3 = __half22float2(hp[3]);                                \
        acc[0] = fmaf(w, f0.x, acc[0]); acc[1] = fmaf(w, f0.y, acc[1]);   \
        acc[2] = fmaf(w, f1.x, acc[2]); acc[3] = fmaf(w, f1.y, acc[3]);   \
        acc[4] = fmaf(w, f2.x, acc[4]); acc[5] = fmaf(w, f2.y, acc[5]);   \
        acc[6] = fmaf(w, f3.x, acc[6]); acc[7] = fmaf(w, f3.y, acc[7]);   \
    }

    uint4 h0 = GATH(r0);
    uint4 h1 = GATH(r1);
    uint4 h2 = GATH(r2);
    uint4 h3;

    int p = beg;
    while (p < end) {
        // phase 0 : pair at p
        h3 = GATH(r3);
        PROC(r0, h0);
        r0 = rec[p + 8 + half];
        p += 2;
        if (p >= end) break;
        // phase 1
        h0 = GATH(r0);
        PROC(r1, h1);
        r1 = rec[p + 8 + half];
        p += 2;
        if (p >= end) break;
        // phase 2
        h1 = GATH(r1);
        PROC(r2, h2);
        r2 = rec[p + 8 + half];
        p += 2;
        if (p >= end) break;
        // phase 3
        h2 = GATH(r2);
        PROC(r3, h3);
        r3 = rec[p + 8 + half];
        p += 2;
    }
#undef GATH
#undef PROC

    // combine the two halves (same node, disjoint edges, same channels)
    l += __shfl_xor(l, 32);
#pragma unroll
    for (int j = 0; j < 8; j++) acc[j] += __shfl_xor(acc[j], 32);

    if (half == 0) {
        float rcp = 1.f / l;
        float4 b0 = *(const float4*)&bias[l32 * 8];
        float4 b1 = *(const float4*)&bias[l32 * 8 + 4];
        float o[8];
        o[0] = fmaf(acc[0], rcp, b0.x); o[1] = fmaf(acc[1], rcp, b0.y);
        o[2] = fmaf(acc[2], rcp, b0.z); o[3] = fmaf(acc[3], rcp, b0.w);
        o[4] = fmaf(acc[4], rcp, b1.x); o[5] = fmaf(acc[5], rcp, b1.y);
        o[6] = fmaf(acc[6], rcp, b1.z); o[7] = fmaf(acc[7], rcp, b1.w);
#pragma unroll
        for (int j = 0; j < 8; j++)
            o[j] = (o[j] > 0.f) ? o[j] : __expf(o[j]) - 1.f;
        if constexpr (OUT_HALF) {
            __half2 q0 = __floats2half2_rn(o[0], o[1]);
            __half2 q1 = __floats2half2_rn(o[2], o[3]);
            __half2 q2 = __floats2half2_rn(o[4], o[5]);
            __half2 q3 = __floats2half2_rn(o[6], o[7]);
            uint4 pk = {*(unsigned*)&q0, *(unsigned*)&q1,
                        *(unsigned*)&q2, *(unsigned*)&q3};
            __half* outh = (__half*)outp;
            *(uint4*)&outh[(size_t)node * 256 + l32 * 8] = pk;
        } else {
            float* outf = (float*)outp;
            *(float4*)&outf[(size_t)node * 256 + l32 * 8] = *(float4*)&o[0];
            *(float4*)&outf[(size_t)node * 256 + l32 * 8 + 4] = *(float4*)&o[4];
        }
    }
}

// ---------------- launch ----------------

extern "C" void kernel_launch(void* const* d_in, const int* in_sizes, int n_in,
                              void* d_out, int out_size, void* d_ws, size_t ws_size,
                              hipStream_t stream) {
    const float* x   = (const float*)d_in[0];
    const int*   ei  = (const int*)d_in[1];
    const float* W1  = (const float*)d_in[2];
    const float* as1 = (const float*)d_in[3];
    const float* ad1 = (const float*)d_in[4];
    const float* b1  = (const float*)d_in[5];
    const float* W2  = (const float*)d_in[6];
    const float* as2 = (const float*)d_in[7];
    const float* ad2 = (const float*)d_in[8];
    const float* b2  = (const float*)d_in[9];
    float* out = (float*)d_out;

    const int N = in_sizes[0] / 128;
    const int E = in_sizes[1] / 2;
    const int Etot = E + N;
    const int EtotMax = (Etot + N + 9) & ~1;  // padded slots + pipeline pad, even
    const int NB = (N + 1023) / 1024;         // scan blocks (<= 64)

    // workspace layout (16B-aligned segments first)
    __half* h_half = (__half*)d_ws;                        // N*256 fp16
    __half* x1_h   = h_half + (size_t)N * 256;             // N*256 fp16 (x / x1)
    uint4*  rec    = (uint4*)(x1_h + (size_t)N * 256);     // EtotMax x 16B
    __half* a_s_h  = (__half*)(rec + EtotMax);             // N*4 fp16
    float*  a_d    = (float*)(a_s_h + (size_t)N * 4);      // N*4 fp32
    __half* Bt1    = (__half*)(a_d + (size_t)N * 4);       // 256*128 fp16
    __half* Bt2    = Bt1 + 256 * 128;                      // 256*256 fp16
    int*    cnt    = (int*)(Bt2 + 256 * 256);              // N
    int*    fill   = cnt + N;                              // N
    int*    row_st = fill + N;                             // N+2 (pad for align)
    int2*   edge_sd = (int2*)(row_st + (N + 2));           // EtotMax x 8B
    int*    partials = (int*)(edge_sd + EtotMax);          // NB+1

    hipMemsetAsync(cnt, 0, sizeof(int) * 2 * (size_t)N, stream);   // cnt + fill
    hipMemsetAsync(edge_sd, 0xFF, sizeof(int2) * (size_t)EtotMax, stream);

    const int xblocks = (N * 32 + 255) / 256;       // x->fp16 blocks
    const int eblocks = (Etot + 255) / 256;         // histogram / scatter blocks
    prep_kernel<<<384 + xblocks + eblocks, 256, 0, stream>>>(
        W1, Bt1, W2, Bt2, x, x1_h, ei, cnt, E, N, xblocks);

    scan_block<<<NB, 1024, 0, stream>>>(cnt, row_st, partials, N);
    scan_add<<<NB, 1024, 0, stream>>>(row_st, partials, N, NB);
    scatter_kernel<<<eblocks, 256, 0, stream>>>(ei, row_st, fill, edge_sd, E, Etot);

    dim3 ggrid(2 * ((N + 127) / 128));
    int ablocks = (N + 3) / 4;          // 4 nodes (waves) per 256-thread block
    int npairs = EtotMax / 2;
    int fblocks = (npairs + 255) / 256;

    // layer 1 (A = x pre-converted to fp16, living in the x1 buffer)
    gemm_mfma<128><<<ggrid, 256, 0, stream>>>(x1_h, Bt1, h_half,
                                              as1, ad1, a_s_h, a_d, N);
    fill_rec<<<fblocks, 256, 0, stream>>>((const int4*)edge_sd, a_s_h, a_d,
                                          rec, npairs);
    gat_aggregate<true><<<ablocks, 256, 0, stream>>>(h_half, rec, row_st,
                                                     b1, x1_h, N);
    // layer 2
    gemm_mfma<256><<<ggrid, 256, 0, stream>>>(x1_h, Bt2, h_half,
                                              as2, ad2, a_s_h, a_d, N);
    fill_rec<<<fblocks, 256, 0, stream>>>((const int4*)edge_sd, a_s_h, a_d,
                                          rec, npairs);
    gat_aggregate<false><<<ablocks, 256, 0, stream>>>(h_half, rec, row_st,
                                                      b2, out, N);
}